// Round 3
// baseline (638.419 us; speedup 1.0000x reference)
//
#include <hip/hip_runtime.h>
#include <hip/hip_fp16.h>

typedef _Float16 half8 __attribute__((ext_vector_type(8)));
typedef _Float16 half4 __attribute__((ext_vector_type(4)));
typedef float floatx4 __attribute__((ext_vector_type(4)));

__device__ __forceinline__ void async_ld16(const void* g, void* l) {
    __builtin_amdgcn_global_load_lds(
        (const __attribute__((address_space(1))) char*)g,
        (__attribute__((address_space(3))) char*)l, 16, 0, 0);
}

__device__ __forceinline__ float elu_f(float v) {
    return v > 0.f ? v : expm1f(v);
}

// Device-scope grid barrier. Counter must be pre-zeroed (prep_light does it).
// Requires all gridDim.x blocks co-resident (enforced via __launch_bounds__
// occupancy arithmetic: 1024 blocks = 4/CU x 256 CU).
__device__ __forceinline__ void grid_barrier(unsigned int* bar, unsigned int target) {
    __syncthreads();
    if (threadIdx.x == 0) {
        __threadfence();                       // release this block's writes
        atomicAdd(bar, 1u);                    // device-scope by default
        while (__hip_atomic_load(bar, __ATOMIC_ACQUIRE, __HIP_MEMORY_SCOPE_AGENT) < target)
            __builtin_amdgcn_s_sleep(1);
        __threadfence();                       // acquire all blocks' writes
    }
    __syncthreads();
}

__device__ __forceinline__ half4 cvt4(const float* src, int j4) {
    float4 f = ((const float4*)src)[j4];
    half4 h; h.x = (_Float16)f.x; h.y = (_Float16)f.y;
    h.z = (_Float16)f.z; h.w = (_Float16)f.w; return h;
}

// ---------------------------------------------------------------------------
// prep_light: X0 [4096][320] = [x|z] fp16; z-cols of h0/h1/h2; gating weights
// fp16; zero the grid-barrier counters.
// ---------------------------------------------------------------------------
__global__ void prep_light(const float* __restrict__ x, const float* __restrict__ z,
                           const float* __restrict__ gW1, const float* __restrict__ gW2,
                           const float* __restrict__ gW3,
                           _Float16* __restrict__ X0,
                           _Float16* __restrict__ h0, _Float16* __restrict__ h1,
                           _Float16* __restrict__ h2,
                           _Float16* __restrict__ gW1c, _Float16* __restrict__ gW2c,
                           _Float16* __restrict__ gW3c,
                           unsigned int* __restrict__ bars)
{
    if (blockIdx.x == 0 && threadIdx.x < 8) bars[threadIdx.x] = 0u;

    const int N_X4  = 4096 * 288 / 4;   // 294912
    const int N_Z4  = 4096 * 32 / 4;    // 32768
    const int N_G14 = 128 * 320 / 4;    // 10240
    const int N_G24 = 128 * 128 / 4;    // 4096
    const int N_G34 = 8 * 128 / 4;      // 256
    const int TOTAL4 = N_X4 + 4 * N_Z4 + N_G14 + N_G24 + N_G34;

    for (int i = blockIdx.x * blockDim.x + threadIdx.x; i < TOTAL4;
         i += gridDim.x * blockDim.x) {
        int j = i;
        if (j < N_X4) {
            int b = j / 72, k4 = j - b * 72;
            *(half4*)(X0 + b * 320 + k4 * 4) = cvt4(x, j);
            continue;
        }
        j -= N_X4;
        if (j < N_Z4) {
            int b = j / 8, k4 = j - b * 8;
            *(half4*)(X0 + b * 320 + 288 + k4 * 4) = cvt4(z, j);
            continue;
        }
        j -= N_Z4;
        if (j < 3 * N_Z4) {
            int buf = j / N_Z4; int r = j - buf * N_Z4;
            int b = r / 8, k4 = r - b * 8;
            _Float16* h = (buf == 0) ? h0 : ((buf == 1) ? h1 : h2);
            *(half4*)(h + b * 544 + 512 + k4 * 4) = cvt4(z, r);
            continue;
        }
        j -= 3 * N_Z4;
        if (j < N_G14) { *(half4*)(gW1c + j * 4) = cvt4(gW1, j); continue; } j -= N_G14;
        if (j < N_G24) { *(half4*)(gW2c + j * 4) = cvt4(gW2, j); continue; } j -= N_G24;
        *(half4*)(gW3c + j * 4) = cvt4(gW3, j);
    }
}

// ---------------------------------------------------------------------------
// gating_and_wconv: blocks 0..31 run the fused gating chain (3 layers +
// softmax) for their 128 rows; blocks 32..1023 convert the 25 MB of expert
// weights fp32->fp16 concurrently (independent work, no barrier needed).
// ---------------------------------------------------------------------------
__launch_bounds__(256)
__global__ void gating_and_wconv(const _Float16* __restrict__ X0,
                                 const _Float16* __restrict__ gW1c,
                                 const _Float16* __restrict__ gW2c,
                                 const _Float16* __restrict__ gW3c,
                                 const float* __restrict__ gb1,
                                 const float* __restrict__ gb2,
                                 const float* __restrict__ gb3,
                                 float* __restrict__ g,
                                 const float* __restrict__ W0, const float* __restrict__ W1,
                                 const float* __restrict__ W2, const float* __restrict__ W3,
                                 _Float16* __restrict__ Wc0, _Float16* __restrict__ Wc1,
                                 _Float16* __restrict__ Wc2, _Float16* __restrict__ Wc3)
{
    __shared__ _Float16 sA[128 * 32];
    __shared__ _Float16 sB[128 * 32];
    __shared__ _Float16 h1t[128 * 136];
    __shared__ _Float16 sW3[8 * 128];

    const int tid = threadIdx.x;

    if (blockIdx.x >= 32) {
        // ---- expert weight conversion ----
        const int N_W04  = 8 * 512 * 320 / 4;   // 327680
        const int N_W124 = 8 * 512 * 544 / 4;   // 557056
        const int N_W34  = 8 * 96 * 512 / 4;    // 98304
        const int TOTAL4 = N_W04 + 2 * N_W124 + N_W34;
        const int nb = gridDim.x - 32;
        for (int i = (blockIdx.x - 32) * blockDim.x + tid; i < TOTAL4;
             i += nb * blockDim.x) {
            int j = i;
            if (j < N_W04)  { *(half4*)(Wc0 + j * 4) = cvt4(W0, j); continue; } j -= N_W04;
            if (j < N_W124) { *(half4*)(Wc1 + j * 4) = cvt4(W1, j); continue; } j -= N_W124;
            if (j < N_W124) { *(half4*)(Wc2 + j * 4) = cvt4(W2, j); continue; } j -= N_W124;
            *(half4*)(Wc3 + j * 4) = cvt4(W3, j);
        }
        return;
    }

    // ---- gating chain for rows m0..m0+127 ----
    const int l = tid & 63;
    const int w = tid >> 6;
    const int wm = w >> 1, wn = w & 1;
    const int m0 = blockIdx.x * 128;

    for (int t = tid; t < 8 * 128; t += 256) sW3[t] = gW3c[t];

    const int sub = l >> 2;
    const int kc  = (l & 3) * 8;
    const int row0 = w * 16 + sub;
    const _Float16* gA0 = X0 + (size_t)(m0 + row0) * 320 + kc;
    const _Float16* gA1 = gA0 + (size_t)64 * 320;
    const _Float16* gB0 = gW1c + (size_t)row0 * 320 + kc;
    const _Float16* gB1 = gW1c + (size_t)(row0 + 64) * 320 + kc;
    _Float16* sA0 = sA + w * 512;
    _Float16* sA1 = sA + 2048 + w * 512;
    _Float16* sB0 = sB + w * 512;
    _Float16* sB1 = sB + 2048 + w * 512;

    const int mi = l & 15, quad = l >> 4;
    const _Float16* rA = sA + (wm * 64 + mi) * 32 + quad * 8;
    const _Float16* rB = sB + (wn * 64 + mi) * 32 + quad * 8;

    floatx4 acc[4][4] = {};

    for (int k0 = 0; k0 < 320; k0 += 32) {
        __syncthreads();
        async_ld16(gA0 + k0, sA0);
        async_ld16(gA1 + k0, sA1);
        async_ld16(gB0 + k0, sB0);
        async_ld16(gB1 + k0, sB1);
        __syncthreads();
        half8 af[4], bf[4];
#pragma unroll
        for (int i = 0; i < 4; i++) af[i] = *(const half8*)(rA + i * 16 * 32);
#pragma unroll
        for (int j = 0; j < 4; j++) bf[j] = *(const half8*)(rB + j * 16 * 32);
#pragma unroll
        for (int i = 0; i < 4; i++)
#pragma unroll
            for (int j = 0; j < 4; j++)
                acc[i][j] = __builtin_amdgcn_mfma_f32_16x16x32_f16(af[i], bf[j], acc[i][j], 0, 0, 0);
    }
    __syncthreads();
#pragma unroll
    for (int i = 0; i < 4; i++)
#pragma unroll
        for (int j = 0; j < 4; j++) {
            int n = wn * 64 + j * 16 + mi;
            float bn = gb1[n];
#pragma unroll
            for (int r = 0; r < 4; r++) {
                int mrel = wm * 64 + i * 16 + quad * 4 + r;
                h1t[mrel * 136 + n] = (_Float16)elu_f(acc[i][j][r] + bn);
            }
        }

    floatx4 acc2[4][4] = {};
    const _Float16* gB20 = gW2c + (size_t)row0 * 128 + kc;
    const _Float16* gB21 = gW2c + (size_t)(row0 + 64) * 128 + kc;
    const _Float16* rA2b = h1t + (wm * 64 + mi) * 136 + quad * 8;
    for (int ks = 0; ks < 4; ks++) {
        __syncthreads();
        async_ld16(gB20 + ks * 32, sB0);
        async_ld16(gB21 + ks * 32, sB1);
        __syncthreads();
        half8 af[4], bf[4];
#pragma unroll
        for (int i = 0; i < 4; i++) af[i] = *(const half8*)(rA2b + i * 16 * 136 + ks * 32);
#pragma unroll
        for (int j = 0; j < 4; j++) bf[j] = *(const half8*)(rB + j * 16 * 32);
#pragma unroll
        for (int i = 0; i < 4; i++)
#pragma unroll
            for (int j = 0; j < 4; j++)
                acc2[i][j] = __builtin_amdgcn_mfma_f32_16x16x32_f16(af[i], bf[j], acc2[i][j], 0, 0, 0);
    }
    __syncthreads();
#pragma unroll
    for (int i = 0; i < 4; i++)
#pragma unroll
        for (int j = 0; j < 4; j++) {
            int n = wn * 64 + j * 16 + mi;
            float bn = gb2[n];
#pragma unroll
            for (int r = 0; r < 4; r++) {
                int mrel = wm * 64 + i * 16 + quad * 4 + r;
                h1t[mrel * 136 + n] = (_Float16)elu_f(acc2[i][j][r] + bn);
            }
        }
    __syncthreads();

    const int e = l >> 3, kk = l & 7;
    for (int rr = 0; rr < 32; rr++) {
        int row = w * 32 + rr;
        const _Float16* hr = h1t + row * 136 + kk * 16;
        const _Float16* wr = sW3 + e * 128 + kk * 16;
        half8 hv0 = *(const half8*)hr;
        half8 hv1 = *(const half8*)(hr + 8);
        half8 wv0 = *(const half8*)wr;
        half8 wv1 = *(const half8*)(wr + 8);
        float s = 0.f;
#pragma unroll
        for (int t = 0; t < 8; t++)
            s += (float)hv0[t] * (float)wv0[t] + (float)hv1[t] * (float)wv1[t];
        s += __shfl_xor(s, 1);
        s += __shfl_xor(s, 2);
        s += __shfl_xor(s, 4);
        float logit = s + gb3[e];
        float mx = logit;
        mx = fmaxf(mx, __shfl_xor(mx, 8));
        mx = fmaxf(mx, __shfl_xor(mx, 16));
        mx = fmaxf(mx, __shfl_xor(mx, 32));
        float ve = __expf(logit - mx);
        float ssum = ve;
        ssum += __shfl_xor(ssum, 1);
        ssum += __shfl_xor(ssum, 2);
        ssum += __shfl_xor(ssum, 4);
        ssum += __shfl_xor(ssum, 8);
        ssum += __shfl_xor(ssum, 16);
        ssum += __shfl_xor(ssum, 32);
        float gv = ve / (ssum * 0.125f);
        if (kk == 0) g[(size_t)(m0 + row) * 8 + e] = gv;
    }
}

// ---------------------------------------------------------------------------
// blend_tile: one 128-row x 16-out-col x 8-expert blended GEMM tile.
// Identical math to the round-2 gemm_blend (verified correct).
// ---------------------------------------------------------------------------
template <bool ELU_ACT, typename OUT_T>
__device__ __forceinline__ void blend_tile(
    const _Float16* __restrict__ A, int lda,
    const _Float16* __restrict__ W, int ldw, int Hdim, int K,
    const float* __restrict__ bias,
    OUT_T* __restrict__ out, int ldo,
    int m0, int o0,
    char* smem_raw, float (*sg)[9], float (*sbias)[16])
{
    _Float16* sA = (_Float16*)smem_raw;
    _Float16* sB = (_Float16*)(smem_raw + 8192);
    float* sredf = (float*)smem_raw;

    const int tid = threadIdx.x;
    const int l = tid & 63;
    const int w = tid >> 6;
    const int wm = w >> 1, wn = w & 1;

    for (int t = tid; t < 128; t += 256)
        sbias[t >> 4][t & 15] = bias[(t >> 4) * Hdim + o0 + (t & 15)];

    const int sub = l >> 2;
    const int kc  = (l & 3) * 8;
    const int row0 = w * 16 + sub;
    const _Float16* gA0 = A + (size_t)(m0 + row0) * lda + kc;
    const _Float16* gA1 = gA0 + (size_t)64 * lda;
    const int c0 = row0, c1 = row0 + 64;
    const _Float16* gB0 = W + (size_t)((c0 >> 4) * Hdim + o0 + (c0 & 15)) * ldw + kc;
    const _Float16* gB1 = W + (size_t)((c1 >> 4) * Hdim + o0 + (c1 & 15)) * ldw + kc;
    _Float16* sA0 = sA + w * 512;
    _Float16* sA1 = sA + 2048 + w * 512;
    _Float16* sB0 = sB + w * 512;
    _Float16* sB1 = sB + 2048 + w * 512;

    const int mi = l & 15, quad = l >> 4;
    const _Float16* rA = sA + (wm * 64 + mi) * 32 + quad * 8;
    const _Float16* rB = sB + (wn * 64 + mi) * 32 + quad * 8;

    floatx4 acc[4][4] = {};

    for (int k0 = 0; k0 < K; k0 += 32) {
        __syncthreads();
        async_ld16(gA0 + k0, sA0);
        async_ld16(gA1 + k0, sA1);
        async_ld16(gB0 + k0, sB0);
        async_ld16(gB1 + k0, sB1);
        __syncthreads();
        half8 af[4], bf[4];
#pragma unroll
        for (int i = 0; i < 4; i++) af[i] = *(const half8*)(rA + i * 16 * 32);
#pragma unroll
        for (int j = 0; j < 4; j++) bf[j] = *(const half8*)(rB + j * 16 * 32);
#pragma unroll
        for (int i = 0; i < 4; i++)
#pragma unroll
            for (int j = 0; j < 4; j++)
                acc[i][j] = __builtin_amdgcn_mfma_f32_16x16x32_f16(af[i], bf[j], acc[i][j], 0, 0, 0);
    }

    float p[4][4];
#pragma unroll
    for (int i = 0; i < 4; i++)
#pragma unroll
        for (int r = 0; r < 4; r++) {
            int mloc = wm * 64 + i * 16 + quad * 4 + r;
            float s = 0.f;
#pragma unroll
            for (int j = 0; j < 4; j++) {
                int e = wn * 4 + j;
                s += sg[mloc][e] * (acc[i][j][r] + sbias[e][mi]);
            }
            p[i][r] = s;
        }

    __syncthreads();
    if (wn == 0) {
#pragma unroll
        for (int i = 0; i < 4; i++)
#pragma unroll
            for (int r = 0; r < 4; r++)
                sredf[(wm * 64 + i * 16 + quad * 4 + r) * 17 + mi] = p[i][r];
    }
    __syncthreads();
    if (wn == 1) {
#pragma unroll
        for (int i = 0; i < 4; i++)
#pragma unroll
            for (int r = 0; r < 4; r++) {
                int mrel = i * 16 + quad * 4 + r;
                float v = p[i][r] + sredf[(wm * 64 + mrel) * 17 + mi];
                if (ELU_ACT) v = elu_f(v);
                out[(size_t)(m0 + wm * 64 + mrel) * ldo + o0 + mi] = (OUT_T)v;
            }
    }
}

// ---------------------------------------------------------------------------
// mega_blend: all 4 blended layers in one persistent kernel.
// grid MUST be 1024 = 4 blocks/CU x 256 CUs (co-residency for grid_barrier).
// LDS 21.5 KB <= 40 KB; launch_bounds(256,4) caps VGPR at 128.
// ---------------------------------------------------------------------------
__launch_bounds__(256, 4)
__global__ void mega_blend(const _Float16* __restrict__ X0,
                           _Float16* __restrict__ h0, _Float16* __restrict__ h1,
                           _Float16* __restrict__ h2,
                           const _Float16* __restrict__ Wc0, const _Float16* __restrict__ Wc1,
                           const _Float16* __restrict__ Wc2, const _Float16* __restrict__ Wc3,
                           const float* __restrict__ g,
                           const float* __restrict__ b0, const float* __restrict__ b1,
                           const float* __restrict__ b2, const float* __restrict__ b3,
                           float* __restrict__ out,
                           unsigned int* __restrict__ bars)
{
    __shared__ __align__(16) char smem_raw[16384];
    __shared__ float sg[128][9];
    __shared__ float sbias[8][16];

    const int tid = threadIdx.x;
    const int id = blockIdx.x;
    const int bx = id & 31, by = id >> 5;
    const int m0 = by * 128, o0 = bx * 16;
    const unsigned int nb = gridDim.x;

    for (int t = tid; t < 128 * 8; t += 256)
        sg[t >> 3][t & 7] = g[(size_t)(m0 + (t >> 3)) * 8 + (t & 7)];

    blend_tile<true, _Float16>(X0, 320, Wc0, 320, 512, 320, b0, h0, 544, m0, o0,
                               smem_raw, sg, sbias);
    grid_barrier(&bars[0], nb);
    blend_tile<true, _Float16>(h0, 544, Wc1, 544, 512, 544, b1, h1, 544, m0, o0,
                               smem_raw, sg, sbias);
    grid_barrier(&bars[1], nb);
    blend_tile<true, _Float16>(h1, 544, Wc2, 544, 512, 544, b2, h2, 544, m0, o0,
                               smem_raw, sg, sbias);
    grid_barrier(&bars[2], nb);

    if (id < 192) {
        const int by4 = id / 6, bx4 = id - by4 * 6;
        const int m04 = by4 * 128, o04 = bx4 * 16;
        for (int t = tid; t < 128 * 8; t += 256)
            sg[t >> 3][t & 7] = g[(size_t)(m04 + (t >> 3)) * 8 + (t & 7)];
        blend_tile<false, float>(h2, 544, Wc3, 512, 96, 512, b3, out, 96, m04, o04,
                                 smem_raw, sg, sbias);
    }
}

// ---------------------------------------------------------------------------
extern "C" void kernel_launch(void* const* d_in, const int* in_sizes, int n_in,
                              void* d_out, int out_size, void* d_ws, size_t ws_size,
                              hipStream_t stream)
{
    (void)in_sizes; (void)n_in; (void)out_size; (void)ws_size;
    const float* x   = (const float*)d_in[0];
    const float* z   = (const float*)d_in[1];
    const float* W0  = (const float*)d_in[2];
    const float* b0  = (const float*)d_in[3];
    const float* W1  = (const float*)d_in[4];
    const float* b1  = (const float*)d_in[5];
    const float* W2  = (const float*)d_in[6];
    const float* b2  = (const float*)d_in[7];
    const float* W3  = (const float*)d_in[8];
    const float* b3  = (const float*)d_in[9];
    const float* gW1 = (const float*)d_in[10];
    const float* gb1 = (const float*)d_in[11];
    const float* gW2 = (const float*)d_in[12];
    const float* gb2 = (const float*)d_in[13];
    const float* gW3 = (const float*)d_in[14];
    const float* gb3 = (const float*)d_in[15];

    char* p = (char*)d_ws;
    auto alloc = [&](size_t n) { char* r = p; p += (n + 255) & ~(size_t)255; return r; };
    _Float16* X0   = (_Float16*)alloc((size_t)4096 * 320 * 2);
    _Float16* h0   = (_Float16*)alloc((size_t)4096 * 544 * 2);
    _Float16* h1   = (_Float16*)alloc((size_t)4096 * 544 * 2);
    _Float16* h2   = (_Float16*)alloc((size_t)4096 * 544 * 2);
    _Float16* Wc0  = (_Float16*)alloc((size_t)8 * 512 * 320 * 2);
    _Float16* Wc1  = (_Float16*)alloc((size_t)8 * 512 * 544 * 2);
    _Float16* Wc2  = (_Float16*)alloc((size_t)8 * 512 * 544 * 2);
    _Float16* Wc3  = (_Float16*)alloc((size_t)8 * 96 * 512 * 2);
    _Float16* gW1c = (_Float16*)alloc((size_t)128 * 320 * 2);
    _Float16* gW2c = (_Float16*)alloc((size_t)128 * 128 * 2);
    _Float16* gW3c = (_Float16*)alloc((size_t)8 * 128 * 2);
    float*    g    = (float*)alloc((size_t)4096 * 8 * 4);
    unsigned int* bars = (unsigned int*)alloc(8 * 4);

    prep_light<<<512, 256, 0, stream>>>(x, z, gW1, gW2, gW3, X0, h0, h1, h2,
                                        gW1c, gW2c, gW3c, bars);

    gating_and_wconv<<<1024, 256, 0, stream>>>(X0, gW1c, gW2c, gW3c, gb1, gb2, gb3, g,
                                               W0, W1, W2, W3, Wc0, Wc1, Wc2, Wc3);

    mega_blend<<<1024, 256, 0, stream>>>(X0, h0, h1, h2, Wc0, Wc1, Wc2, Wc3, g,
                                         b0, b1, b2, b3, (float*)d_out, bars);
}

// Round 4
// 224.298 us; speedup vs baseline: 2.8463x; 2.8463x over previous
//
#include <hip/hip_runtime.h>
#include <hip/hip_fp16.h>

typedef _Float16 half8 __attribute__((ext_vector_type(8)));
typedef _Float16 half4 __attribute__((ext_vector_type(4)));
typedef float floatx4 __attribute__((ext_vector_type(4)));

__device__ __forceinline__ void async_ld16(const void* g, void* l) {
    __builtin_amdgcn_global_load_lds(
        (const __attribute__((address_space(1))) char*)g,
        (__attribute__((address_space(3))) char*)l, 16, 0, 0);
}

__device__ __forceinline__ float elu_f(float v) {
    return v > 0.f ? v : expm1f(v);
}

__device__ __forceinline__ half4 cvt4(const float* src, int j4) {
    float4 f = ((const float4*)src)[j4];
    half4 h; h.x = (_Float16)f.x; h.y = (_Float16)f.y;
    h.z = (_Float16)f.z; h.w = (_Float16)f.w; return h;
}

__device__ __forceinline__ half8 cvt8(const float* src) {
    float4 f0 = ((const float4*)src)[0];
    float4 f1 = ((const float4*)src)[1];
    half8 h;
    h[0] = (_Float16)f0.x; h[1] = (_Float16)f0.y; h[2] = (_Float16)f0.z; h[3] = (_Float16)f0.w;
    h[4] = (_Float16)f1.x; h[5] = (_Float16)f1.y; h[6] = (_Float16)f1.z; h[7] = (_Float16)f1.w;
    return h;
}

// ---------------------------------------------------------------------------
// gating_and_wconv: blocks 0..31 run the full gating chain SELF-CONTAINED
// (they convert their own fp32 x/z/gW tiles through registers); blocks
// 32..1023 convert everything the blend layers need:
//   X0 [4096][320] = [x|z] fp16
//   h0/h1/h2 [4096][576]: cols 512..543 = z, cols 544..575 = 0  (K-pad)
//   Wc0 [8*512][320], Wc1/Wc2 [8*512][576] (cols 544..575 = 0), Wc3 [8*96][512]
// ---------------------------------------------------------------------------
__launch_bounds__(256)
__global__ void gating_and_wconv(const float* __restrict__ x, const float* __restrict__ z,
                                 const float* __restrict__ gW1, const float* __restrict__ gW2,
                                 const float* __restrict__ gW3,
                                 const float* __restrict__ gb1, const float* __restrict__ gb2,
                                 const float* __restrict__ gb3,
                                 float* __restrict__ g,
                                 const float* __restrict__ W0, const float* __restrict__ W1,
                                 const float* __restrict__ W2, const float* __restrict__ W3,
                                 _Float16* __restrict__ X0,
                                 _Float16* __restrict__ h0, _Float16* __restrict__ h1,
                                 _Float16* __restrict__ h2,
                                 _Float16* __restrict__ Wc0, _Float16* __restrict__ Wc1,
                                 _Float16* __restrict__ Wc2, _Float16* __restrict__ Wc3)
{
    const int tid = threadIdx.x;

    if (blockIdx.x >= 32) {
        // ---- conversion for the blend layers ----
        const int S0 = 294912;                // X0 <- x   (row/72)
        const int S1 = 32768;                 // X0 <- z   (row/8)
        const int S2 = 327680;                // Wc0       (straight)
        const int S3 = 589824;                // Wc1 <- W1 (row/144, pad)
        const int S4 = 589824;                // Wc2 <- W2
        const int S5 = 98304;                 // Wc3       (straight)
        const int S6 = 196608;                // h z-cols + pad (3 x 4096 x 16)
        const int TOTAL = S0 + S1 + S2 + S3 + S4 + S5 + S6;
        const int nb = gridDim.x - 32;
        const half4 hz = {};
        for (int i = (blockIdx.x - 32) * blockDim.x + tid; i < TOTAL;
             i += nb * blockDim.x) {
            int j = i;
            if (j < S0) {
                int r = j / 72, c = j - r * 72;
                *(half4*)(X0 + r * 320 + c * 4) = cvt4(x, j);
                continue;
            }
            j -= S0;
            if (j < S1) {
                int r = j / 8, c = j - r * 8;
                *(half4*)(X0 + r * 320 + 288 + c * 4) = cvt4(z, j);
                continue;
            }
            j -= S1;
            if (j < S2) { *(half4*)(Wc0 + j * 4) = cvt4(W0, j); continue; }
            j -= S2;
            if (j < S3) {
                int r = j / 144, c = j - r * 144;
                *(half4*)(Wc1 + r * 576 + c * 4) = (c < 136) ? cvt4(W1, r * 136 + c) : hz;
                continue;
            }
            j -= S3;
            if (j < S4) {
                int r = j / 144, c = j - r * 144;
                *(half4*)(Wc2 + r * 576 + c * 4) = (c < 136) ? cvt4(W2, r * 136 + c) : hz;
                continue;
            }
            j -= S4;
            if (j < S5) { *(half4*)(Wc3 + j * 4) = cvt4(W3, j); continue; }
            j -= S5;
            // S6: h z-cols + zero pad
            int buf = j >> 16;                 // /65536
            int r2 = j & 65535;
            int row = r2 >> 4, c = r2 & 15;
            _Float16* h = (buf == 0) ? h0 : ((buf == 1) ? h1 : h2);
            *(half4*)(h + row * 576 + 512 + c * 4) = (c < 8) ? cvt4(z, row * 8 + c) : hz;
        }
        return;
    }

    // ---- gating chain for rows m0..m0+127 (self-contained fp32->fp16) ----
    __shared__ _Float16 sA[128 * 32];
    __shared__ _Float16 sB[128 * 32];
    __shared__ _Float16 h1t[128 * 136];
    __shared__ _Float16 sW3[8 * 128];

    const int l = tid & 63;
    const int w = tid >> 6;
    const int wm = w >> 1, wn = w & 1;
    const int m0 = blockIdx.x * 128;

    for (int t = tid; t < 8 * 128; t += 256) sW3[t] = (_Float16)gW3[t];

    const int sub = l >> 2;          // 0..15
    const int kc  = (l & 3) * 8;     // 0,8,16,24
    const int row0 = w * 16 + sub;   // 0..63

    const int mi = l & 15, quad = l >> 4;
    const _Float16* rA = sA + (wm * 64 + mi) * 32 + quad * 8;
    const _Float16* rB = sB + (wn * 64 + mi) * 32 + quad * 8;

    floatx4 acc[4][4] = {};

    // GEMM1: K=320, A = [x|z] rows m0.., B = gW1 (both fp32, reg-convert)
    for (int k0 = 0; k0 < 320; k0 += 32) {
        half8 a0, a1, b0, b1;
        if (k0 < 288) {
            a0 = cvt8(x + (size_t)(m0 + row0) * 288 + k0 + kc);
            a1 = cvt8(x + (size_t)(m0 + row0 + 64) * 288 + k0 + kc);
        } else {
            a0 = cvt8(z + (size_t)(m0 + row0) * 32 + kc);
            a1 = cvt8(z + (size_t)(m0 + row0 + 64) * 32 + kc);
        }
        b0 = cvt8(gW1 + (size_t)row0 * 320 + k0 + kc);
        b1 = cvt8(gW1 + (size_t)(row0 + 64) * 320 + k0 + kc);
        __syncthreads();
        *(half8*)(sA + row0 * 32 + kc) = a0;
        *(half8*)(sA + (row0 + 64) * 32 + kc) = a1;
        *(half8*)(sB + row0 * 32 + kc) = b0;
        *(half8*)(sB + (row0 + 64) * 32 + kc) = b1;
        __syncthreads();
        half8 af[4], bf[4];
#pragma unroll
        for (int i = 0; i < 4; i++) af[i] = *(const half8*)(rA + i * 16 * 32);
#pragma unroll
        for (int j = 0; j < 4; j++) bf[j] = *(const half8*)(rB + j * 16 * 32);
#pragma unroll
        for (int i = 0; i < 4; i++)
#pragma unroll
            for (int j = 0; j < 4; j++)
                acc[i][j] = __builtin_amdgcn_mfma_f32_16x16x32_f16(af[i], bf[j], acc[i][j], 0, 0, 0);
    }
    __syncthreads();
#pragma unroll
    for (int i = 0; i < 4; i++)
#pragma unroll
        for (int j = 0; j < 4; j++) {
            int n = wn * 64 + j * 16 + mi;
            float bn = gb1[n];
#pragma unroll
            for (int r = 0; r < 4; r++) {
                int mrel = wm * 64 + i * 16 + quad * 4 + r;
                h1t[mrel * 136 + n] = (_Float16)elu_f(acc[i][j][r] + bn);
            }
        }

    // GEMM2: K=128, A = h1t (LDS), B = gW2 fp32 reg-converted
    floatx4 acc2[4][4] = {};
    const _Float16* rA2b = h1t + (wm * 64 + mi) * 136 + quad * 8;
    for (int ks = 0; ks < 4; ks++) {
        half8 b0 = cvt8(gW2 + (size_t)row0 * 128 + ks * 32 + kc);
        half8 b1 = cvt8(gW2 + (size_t)(row0 + 64) * 128 + ks * 32 + kc);
        __syncthreads();
        *(half8*)(sB + row0 * 32 + kc) = b0;
        *(half8*)(sB + (row0 + 64) * 32 + kc) = b1;
        __syncthreads();
        half8 af[4], bf[4];
#pragma unroll
        for (int i = 0; i < 4; i++) af[i] = *(const half8*)(rA2b + i * 16 * 136 + ks * 32);
#pragma unroll
        for (int j = 0; j < 4; j++) bf[j] = *(const half8*)(rB + j * 16 * 32);
#pragma unroll
        for (int i = 0; i < 4; i++)
#pragma unroll
            for (int j = 0; j < 4; j++)
                acc2[i][j] = __builtin_amdgcn_mfma_f32_16x16x32_f16(af[i], bf[j], acc2[i][j], 0, 0, 0);
    }
    __syncthreads();
#pragma unroll
    for (int i = 0; i < 4; i++)
#pragma unroll
        for (int j = 0; j < 4; j++) {
            int n = wn * 64 + j * 16 + mi;
            float bn = gb2[n];
#pragma unroll
            for (int r = 0; r < 4; r++) {
                int mrel = wm * 64 + i * 16 + quad * 4 + r;
                h1t[mrel * 136 + n] = (_Float16)elu_f(acc2[i][j][r] + bn);
            }
        }
    __syncthreads();

    // gate3 + softmax
    const int e = l >> 3, kk = l & 7;
    for (int rr = 0; rr < 32; rr++) {
        int row = w * 32 + rr;
        const _Float16* hr = h1t + row * 136 + kk * 16;
        const _Float16* wr = sW3 + e * 128 + kk * 16;
        half8 hv0 = *(const half8*)hr;
        half8 hv1 = *(const half8*)(hr + 8);
        half8 wv0 = *(const half8*)wr;
        half8 wv1 = *(const half8*)(wr + 8);
        float s = 0.f;
#pragma unroll
        for (int t = 0; t < 8; t++)
            s += (float)hv0[t] * (float)wv0[t] + (float)hv1[t] * (float)wv1[t];
        s += __shfl_xor(s, 1);
        s += __shfl_xor(s, 2);
        s += __shfl_xor(s, 4);
        float logit = s + gb3[e];
        float mx = logit;
        mx = fmaxf(mx, __shfl_xor(mx, 8));
        mx = fmaxf(mx, __shfl_xor(mx, 16));
        mx = fmaxf(mx, __shfl_xor(mx, 32));
        float ve = __expf(logit - mx);
        float ssum = ve;
        ssum += __shfl_xor(ssum, 1);
        ssum += __shfl_xor(ssum, 2);
        ssum += __shfl_xor(ssum, 4);
        ssum += __shfl_xor(ssum, 8);
        ssum += __shfl_xor(ssum, 16);
        ssum += __shfl_xor(ssum, 32);
        float gv = ve / (ssum * 0.125f);
        if (kk == 0) g[(size_t)(m0 + row) * 8 + e] = gv;
    }
}

// ---------------------------------------------------------------------------
// blended expert GEMM, BK=64:
//   out[m][o] = act( sum_e g[m][e]*( sum_k A[m][k]*W[e*Hdim+o][k] + bias[e*Hdim+o] ) )
// 128 rows x (16 o-cols x 8 experts) per block; K multiple of 64.
// LDS tiles 128x64 fp16 with XOR-swizzled 16B chunks: LDS[row][chunk j]
// holds global chunk (j ^ (row&7)); staging keeps global_load_lds's
// wave-uniform-base + lane*16 constraint; ds_read_b128 stays 2-way (free).
// Waves 0,1 stage A (64 rows each); waves 2,3 stage B. 37.9 KB LDS,
// (256,4): 64 VGPR + 64 AGPR -> 4 blocks/CU, 1024-block grid co-resident.
// ---------------------------------------------------------------------------
template <bool ELU_ACT, typename OUT_T>
__launch_bounds__(256, 4)
__global__ void blend64(const _Float16* __restrict__ A, int lda,
                        const _Float16* __restrict__ W, int ldw,
                        int Hdim, int K,
                        const float* __restrict__ g,
                        const float* __restrict__ bias,
                        OUT_T* __restrict__ out, int ldo)
{
    __shared__ __align__(16) char smem_raw[32768];
    _Float16* sA = (_Float16*)smem_raw;            // [128][64]
    _Float16* sB = (_Float16*)(smem_raw + 16384);  // [128][64]
    float* sredf = (float*)smem_raw;               // [2][64][17] overlay (epilogue)
    __shared__ float sg[128][9];
    __shared__ float sbias[8][16];

    const int tid = threadIdx.x;
    const int l = tid & 63;
    const int w = tid >> 6;
    const int wm = w >> 1, wn = w & 1;
    const int o0 = blockIdx.x * 16;
    const int m0 = blockIdx.y * 128;

    for (int t = tid; t < 128 * 8; t += 256)
        sg[t >> 3][t & 7] = g[(size_t)(m0 + (t >> 3)) * 8 + (t & 7)];
    for (int t = tid; t < 128; t += 256)
        sbias[t >> 4][t & 15] = bias[(t >> 4) * Hdim + o0 + (t & 15)];

    // staging geometry
    const int lr = l >> 3;              // row within 8-row chunk group
    const int lc = l & 7;               // dest 16B-chunk within row
    const int swz = lc ^ lr;            // src chunk (XOR swizzle)

    // A stagers (waves 0,1): rows w*64 + c*8 + lr
    const _Float16* gAp = A + (size_t)(m0 + w * 64 + lr) * lda + swz * 8;   // w<2 only
    _Float16* lAp = sA + w * 4096;                                          // uniform
    // B stagers (waves 2,3): tile-cols (w-2)*64 + c*8 + lr
    const int wb = w - 2;
    const int eb = wb * 4;                       // base expert for even chunks
    const _Float16* gBe = W + ((size_t)eb * Hdim + o0 + lr) * ldw + swz * 8;
    const _Float16* gBo = gBe + (size_t)8 * ldw; // col +8 (odd chunks)
    _Float16* lBp = sB + wb * 4096;

    // fragment read pointers (XOR-compensated): row&7 == mi&7
    const int mi = l & 15, quad = l >> 4;
    const int cswz = mi & 7;
    const int offh0 = ((quad ^ cswz) * 8);
    const int offh1 = (((quad + 4) ^ cswz) * 8);
    const _Float16* rAb = sA + (wm * 64 + mi) * 64;
    const _Float16* rBb = sB + (wn * 64 + mi) * 64;

    floatx4 acc[4][4] = {};

    for (int k0 = 0; k0 < K; k0 += 64) {
        __syncthreads();
        if (w < 2) {
            const _Float16* gp = gAp + k0;
            _Float16* lp = lAp;
#pragma unroll
            for (int c = 0; c < 8; c++) {
                async_ld16(gp, lp);
                gp += (size_t)8 * lda;
                lp += 512;
            }
        } else {
            const _Float16* ge = gBe + k0;
            const _Float16* go = gBo + k0;
            _Float16* lp = lBp;
#pragma unroll
            for (int c2 = 0; c2 < 4; c2++) {
                async_ld16(ge, lp); lp += 512;
                async_ld16(go, lp); lp += 512;
                ge += (size_t)Hdim * ldw;
                go += (size_t)Hdim * ldw;
            }
        }
        __syncthreads();
#pragma unroll
        for (int h = 0; h < 2; h++) {
            const int off = h ? offh1 : offh0;
            half8 af[4], bf[4];
#pragma unroll
            for (int i = 0; i < 4; i++) af[i] = *(const half8*)(rAb + i * 1024 + off);
#pragma unroll
            for (int j = 0; j < 4; j++) bf[j] = *(const half8*)(rBb + j * 1024 + off);
#pragma unroll
            for (int i = 0; i < 4; i++)
#pragma unroll
                for (int j = 0; j < 4; j++)
                    acc[i][j] = __builtin_amdgcn_mfma_f32_16x16x32_f16(af[i], bf[j], acc[i][j], 0, 0, 0);
        }
    }

    // blend epilogue: this wave's experts e = wn*4 + j
    float p[4][4];
#pragma unroll
    for (int i = 0; i < 4; i++)
#pragma unroll
        for (int r = 0; r < 4; r++) {
            int mloc = wm * 64 + i * 16 + quad * 4 + r;
            float s = 0.f;
#pragma unroll
            for (int j = 0; j < 4; j++) {
                int e = wn * 4 + j;
                s += sg[mloc][e] * (acc[i][j][r] + sbias[e][mi]);
            }
            p[i][r] = s;
        }

    __syncthreads();   // staging LDS dead; overlay sred
    if (wn == 0) {
#pragma unroll
        for (int i = 0; i < 4; i++)
#pragma unroll
            for (int r = 0; r < 4; r++)
                sredf[(wm * 64 + i * 16 + quad * 4 + r) * 17 + mi] = p[i][r];
    }
    __syncthreads();
    if (wn == 1) {
#pragma unroll
        for (int i = 0; i < 4; i++)
#pragma unroll
            for (int r = 0; r < 4; r++) {
                int mrel = i * 16 + quad * 4 + r;
                float v = p[i][r] + sredf[(wm * 64 + mrel) * 17 + mi];
                if (ELU_ACT) v = elu_f(v);
                out[(size_t)(m0 + wm * 64 + mrel) * ldo + o0 + mi] = (OUT_T)v;
            }
    }
}

// ---------------------------------------------------------------------------
extern "C" void kernel_launch(void* const* d_in, const int* in_sizes, int n_in,
                              void* d_out, int out_size, void* d_ws, size_t ws_size,
                              hipStream_t stream)
{
    (void)in_sizes; (void)n_in; (void)out_size; (void)ws_size;
    const float* x   = (const float*)d_in[0];
    const float* z   = (const float*)d_in[1];
    const float* W0  = (const float*)d_in[2];
    const float* b0  = (const float*)d_in[3];
    const float* W1  = (const float*)d_in[4];
    const float* b1  = (const float*)d_in[5];
    const float* W2  = (const float*)d_in[6];
    const float* b2  = (const float*)d_in[7];
    const float* W3  = (const float*)d_in[8];
    const float* b3  = (const float*)d_in[9];
    const float* gW1 = (const float*)d_in[10];
    const float* gb1 = (const float*)d_in[11];
    const float* gW2 = (const float*)d_in[12];
    const float* gb2 = (const float*)d_in[13];
    const float* gW3 = (const float*)d_in[14];
    const float* gb3 = (const float*)d_in[15];

    char* p = (char*)d_ws;
    auto alloc = [&](size_t n) { char* r = p; p += (n + 255) & ~(size_t)255; return r; };
    _Float16* X0   = (_Float16*)alloc((size_t)4096 * 320 * 2);
    _Float16* h0   = (_Float16*)alloc((size_t)4096 * 576 * 2);
    _Float16* h1   = (_Float16*)alloc((size_t)4096 * 576 * 2);
    _Float16* h2   = (_Float16*)alloc((size_t)4096 * 576 * 2);
    _Float16* Wc0  = (_Float16*)alloc((size_t)8 * 512 * 320 * 2);
    _Float16* Wc1  = (_Float16*)alloc((size_t)8 * 512 * 576 * 2);
    _Float16* Wc2  = (_Float16*)alloc((size_t)8 * 512 * 576 * 2);
    _Float16* Wc3  = (_Float16*)alloc((size_t)8 * 96 * 512 * 2);
    float*    g    = (float*)alloc((size_t)4096 * 8 * 4);

    gating_and_wconv<<<1024, 256, 0, stream>>>(x, z, gW1, gW2, gW3, gb1, gb2, gb3, g,
                                               W0, W1, W2, W3, X0, h0, h1, h2,
                                               Wc0, Wc1, Wc2, Wc3);

    blend64<true, _Float16><<<dim3(32, 32), 256, 0, stream>>>(X0, 320, Wc0, 320, 512, 320, g, b0, h0, 576);
    blend64<true, _Float16><<<dim3(32, 32), 256, 0, stream>>>(h0, 576, Wc1, 576, 512, 576, g, b1, h1, 576);
    blend64<true, _Float16><<<dim3(32, 32), 256, 0, stream>>>(h1, 576, Wc2, 576, 512, 576, g, b2, h2, 576);
    blend64<false, float><<<dim3(6, 32), 256, 0, stream>>>(h2, 576, Wc3, 512, 96, 512, g, b3, (float*)d_out, 96);
}

// Round 5
// 223.674 us; speedup vs baseline: 2.8542x; 1.0028x over previous
//
#include <hip/hip_runtime.h>
#include <hip/hip_fp16.h>

typedef _Float16 half8 __attribute__((ext_vector_type(8)));
typedef _Float16 half4 __attribute__((ext_vector_type(4)));
typedef float floatx4 __attribute__((ext_vector_type(4)));

__device__ __forceinline__ void async_ld16(const void* g, void* l) {
    __builtin_amdgcn_global_load_lds(
        (const __attribute__((address_space(1))) char*)g,
        (__attribute__((address_space(3))) char*)l, 16, 0, 0);
}

// fast ELU: __expf is the HW v_exp_f32 path; |err| vs expm1f <= ~1e-7,
// negligible against fp16 storage rounding (2^-11).
__device__ __forceinline__ float elu_f(float v) {
    return v > 0.f ? v : (__expf(v) - 1.f);
}

__device__ __forceinline__ half4 cvt4(const float* src, int j4) {
    float4 f = ((const float4*)src)[j4];
    half4 h; h.x = (_Float16)f.x; h.y = (_Float16)f.y;
    h.z = (_Float16)f.z; h.w = (_Float16)f.w; return h;
}

__device__ __forceinline__ half8 cvt8(const float* src) {
    float4 f0 = ((const float4*)src)[0];
    float4 f1 = ((const float4*)src)[1];
    half8 h;
    h[0] = (_Float16)f0.x; h[1] = (_Float16)f0.y; h[2] = (_Float16)f0.z; h[3] = (_Float16)f0.w;
    h[4] = (_Float16)f1.x; h[5] = (_Float16)f1.y; h[6] = (_Float16)f1.z; h[7] = (_Float16)f1.w;
    return h;
}

// ---------------------------------------------------------------------------
// gating_conv: blocks 0..63 = barrier-free wave-level gating (each wave owns
// 16 rows, full 3-layer chain + softmax in registers, per-wave LDS scratch
// for the C-layout -> A-layout transpose between layers — NO __syncthreads).
// Blocks 64..1023 = fp32->fp16 conversion of everything the blends need:
//   X0 [4096][320] = [x|z]
//   h0/h1/h2 [4096][576]: cols 512..543 = z, 544..575 = 0 (K-pad)
//   Wc0 [8*512][320], Wc1/Wc2 [8*512][576] (pad cols 0), Wc3 [8*96][512]
// ---------------------------------------------------------------------------
__launch_bounds__(256)
__global__ void gating_conv(const float* __restrict__ x, const float* __restrict__ z,
                            const float* __restrict__ gW1, const float* __restrict__ gW2,
                            const float* __restrict__ gW3,
                            const float* __restrict__ gb1, const float* __restrict__ gb2,
                            const float* __restrict__ gb3,
                            float* __restrict__ g,
                            const float* __restrict__ W0, const float* __restrict__ W1,
                            const float* __restrict__ W2, const float* __restrict__ W3,
                            _Float16* __restrict__ X0,
                            _Float16* __restrict__ h0, _Float16* __restrict__ h1,
                            _Float16* __restrict__ h2,
                            _Float16* __restrict__ Wc0, _Float16* __restrict__ Wc1,
                            _Float16* __restrict__ Wc2, _Float16* __restrict__ Wc3)
{
    __shared__ _Float16 Tbuf[4 * 2 * 16 * 136];   // per-wave [2][16][136]

    const int tid = threadIdx.x;

    if (blockIdx.x >= 64) {
        // ---- conversion for the blend layers ----
        const int S0 = 294912;                // X0 <- x   (row/72)
        const int S1 = 32768;                 // X0 <- z   (row/8)
        const int S2 = 327680;                // Wc0       (straight)
        const int S3 = 589824;                // Wc1 <- W1 (row/144, pad)
        const int S4 = 589824;                // Wc2 <- W2
        const int S5 = 98304;                 // Wc3       (straight)
        const int S6 = 196608;                // h z-cols + pad (3 x 4096 x 16)
        const int TOTAL = S0 + S1 + S2 + S3 + S4 + S5 + S6;
        const int nb = gridDim.x - 64;
        const half4 hz = {};
        for (int i = (blockIdx.x - 64) * blockDim.x + tid; i < TOTAL;
             i += nb * blockDim.x) {
            int j = i;
            if (j < S0) {
                int r = j / 72, c = j - r * 72;
                *(half4*)(X0 + r * 320 + c * 4) = cvt4(x, j);
                continue;
            }
            j -= S0;
            if (j < S1) {
                int r = j / 8, c = j - r * 8;
                *(half4*)(X0 + r * 320 + 288 + c * 4) = cvt4(z, j);
                continue;
            }
            j -= S1;
            if (j < S2) { *(half4*)(Wc0 + j * 4) = cvt4(W0, j); continue; }
            j -= S2;
            if (j < S3) {
                int r = j / 144, c = j - r * 144;
                *(half4*)(Wc1 + r * 576 + c * 4) = (c < 136) ? cvt4(W1, r * 136 + c) : hz;
                continue;
            }
            j -= S3;
            if (j < S4) {
                int r = j / 144, c = j - r * 144;
                *(half4*)(Wc2 + r * 576 + c * 4) = (c < 136) ? cvt4(W2, r * 136 + c) : hz;
                continue;
            }
            j -= S4;
            if (j < S5) { *(half4*)(Wc3 + j * 4) = cvt4(W3, j); continue; }
            j -= S5;
            int buf = j >> 16;
            int r2 = j & 65535;
            int row = r2 >> 4, c = r2 & 15;
            _Float16* h = (buf == 0) ? h0 : ((buf == 1) ? h1 : h2);
            *(half4*)(h + row * 576 + 512 + c * 4) = (c < 8) ? cvt4(z, row * 8 + c) : hz;
        }
        return;
    }

    // ---- wave-level gating: wave handles rows mrow..mrow+15 ----
    const int l = tid & 63;
    const int w = tid >> 6;
    const int quad = l >> 4;          // 0..3
    const int mi = l & 15;
    const int kq = quad * 8;          // k-offset within 32-chunk
    const int mrow = (blockIdx.x * 4 + w) * 16;

    _Float16* T1 = Tbuf + w * (2 * 16 * 136);
    _Float16* T2 = T1 + 16 * 136;

    // ---- layer 1: [x|z] (K=320) @ gW1^T -> 128, elu ----
    floatx4 acc1[8] = {};
    for (int kc = 0; kc < 10; kc++) {
        const int k0 = kc * 32;
        half8 a = (k0 < 288) ? cvt8(x + (size_t)(mrow + mi) * 288 + k0 + kq)
                             : cvt8(z + (size_t)(mrow + mi) * 32 + kq);
#pragma unroll
        for (int t = 0; t < 8; t++) {
            half8 b = cvt8(gW1 + (size_t)(t * 16 + mi) * 320 + k0 + kq);
            acc1[t] = __builtin_amdgcn_mfma_f32_16x16x32_f16(a, b, acc1[t], 0, 0, 0);
        }
    }
#pragma unroll
    for (int t = 0; t < 8; t++) {
        const int n = t * 16 + mi;
        const float bn = gb1[n];
#pragma unroll
        for (int r = 0; r < 4; r++)
            T1[(quad * 4 + r) * 136 + n] = (_Float16)elu_f(acc1[t][r] + bn);
    }

    // ---- layer 2: T1 (K=128) @ gW2^T -> 128, elu ----
    floatx4 acc2[8] = {};
#pragma unroll
    for (int kc = 0; kc < 4; kc++) {
        const int k0 = kc * 32;
        half8 a = *(const half8*)(T1 + mi * 136 + k0 + kq);
#pragma unroll
        for (int t = 0; t < 8; t++) {
            half8 b = cvt8(gW2 + (size_t)(t * 16 + mi) * 128 + k0 + kq);
            acc2[t] = __builtin_amdgcn_mfma_f32_16x16x32_f16(a, b, acc2[t], 0, 0, 0);
        }
    }
#pragma unroll
    for (int t = 0; t < 8; t++) {
        const int n = t * 16 + mi;
        const float bn = gb2[n];
#pragma unroll
        for (int r = 0; r < 4; r++)
            T2[(quad * 4 + r) * 136 + n] = (_Float16)elu_f(acc2[t][r] + bn);
    }

    // ---- layer 3: T2 (K=128) @ gW3^T -> 8 logits, softmax ----
    floatx4 acc3 = {};
#pragma unroll
    for (int kc = 0; kc < 4; kc++) {
        const int k0 = kc * 32;
        half8 a = *(const half8*)(T2 + mi * 136 + k0 + kq);
        half8 b = (mi < 8) ? cvt8(gW3 + (size_t)mi * 128 + k0 + kq) : half8{};
        acc3 = __builtin_amdgcn_mfma_f32_16x16x32_f16(a, b, acc3, 0, 0, 0);
    }
    const float gb = gb3[mi & 7];
#pragma unroll
    for (int r = 0; r < 4; r++) {
        float logit = acc3[r] + gb;            // lanes mi>=8: garbage, isolated
        float mx = logit;
        mx = fmaxf(mx, __shfl_xor(mx, 1));
        mx = fmaxf(mx, __shfl_xor(mx, 2));
        mx = fmaxf(mx, __shfl_xor(mx, 4));     // xor{1,2,4} stays within mi&8 group
        float e = __expf(logit - mx);
        float s = e;
        s += __shfl_xor(s, 1);
        s += __shfl_xor(s, 2);
        s += __shfl_xor(s, 4);
        if (mi < 8)
            g[(size_t)(mrow + quad * 4 + r) * 8 + mi] = e / s;
    }
}

// ---------------------------------------------------------------------------
// blended expert GEMM, BK=64 (unchanged from round 4 — known-good):
//   out[m][o] = act( sum_e g[m][e]*( sum_k A[m][k]*W[e*Hdim+o][k] + bias[e*Hdim+o] ) )
// ---------------------------------------------------------------------------
template <bool ELU_ACT, typename OUT_T>
__launch_bounds__(256, 4)
__global__ void blend64(const _Float16* __restrict__ A, int lda,
                        const _Float16* __restrict__ W, int ldw,
                        int Hdim, int K,
                        const float* __restrict__ g,
                        const float* __restrict__ bias,
                        OUT_T* __restrict__ out, int ldo)
{
    __shared__ __align__(16) char smem_raw[32768];
    _Float16* sA = (_Float16*)smem_raw;            // [128][64]
    _Float16* sB = (_Float16*)(smem_raw + 16384);  // [128][64]
    float* sredf = (float*)smem_raw;               // [2][64][17] overlay (epilogue)
    __shared__ float sg[128][9];
    __shared__ float sbias[8][16];

    const int tid = threadIdx.x;
    const int l = tid & 63;
    const int w = tid >> 6;
    const int wm = w >> 1, wn = w & 1;
    const int o0 = blockIdx.x * 16;
    const int m0 = blockIdx.y * 128;

    for (int t = tid; t < 128 * 8; t += 256)
        sg[t >> 3][t & 7] = g[(size_t)(m0 + (t >> 3)) * 8 + (t & 7)];
    for (int t = tid; t < 128; t += 256)
        sbias[t >> 4][t & 15] = bias[(t >> 4) * Hdim + o0 + (t & 15)];

    const int lr = l >> 3;
    const int lc = l & 7;
    const int swz = lc ^ lr;

    const _Float16* gAp = A + (size_t)(m0 + w * 64 + lr) * lda + swz * 8;
    _Float16* lAp = sA + w * 4096;
    const int wb = w - 2;
    const int eb = wb * 4;
    const _Float16* gBe = W + ((size_t)eb * Hdim + o0 + lr) * ldw + swz * 8;
    const _Float16* gBo = gBe + (size_t)8 * ldw;
    _Float16* lBp = sB + wb * 4096;

    const int mi = l & 15, quad = l >> 4;
    const int cswz = mi & 7;
    const int offh0 = ((quad ^ cswz) * 8);
    const int offh1 = (((quad + 4) ^ cswz) * 8);
    const _Float16* rAb = sA + (wm * 64 + mi) * 64;
    const _Float16* rBb = sB + (wn * 64 + mi) * 64;

    floatx4 acc[4][4] = {};

    for (int k0 = 0; k0 < K; k0 += 64) {
        __syncthreads();
        if (w < 2) {
            const _Float16* gp = gAp + k0;
            _Float16* lp = lAp;
#pragma unroll
            for (int c = 0; c < 8; c++) {
                async_ld16(gp, lp);
                gp += (size_t)8 * lda;
                lp += 512;
            }
        } else {
            const _Float16* ge = gBe + k0;
            const _Float16* go = gBo + k0;
            _Float16* lp = lBp;
#pragma unroll
            for (int c2 = 0; c2 < 4; c2++) {
                async_ld16(ge, lp); lp += 512;
                async_ld16(go, lp); lp += 512;
                ge += (size_t)Hdim * ldw;
                go += (size_t)Hdim * ldw;
            }
        }
        __syncthreads();
#pragma unroll
        for (int h = 0; h < 2; h++) {
            const int off = h ? offh1 : offh0;
            half8 af[4], bf[4];
#pragma unroll
            for (int i = 0; i < 4; i++) af[i] = *(const half8*)(rAb + i * 1024 + off);
#pragma unroll
            for (int j = 0; j < 4; j++) bf[j] = *(const half8*)(rBb + j * 1024 + off);
#pragma unroll
            for (int i = 0; i < 4; i++)
#pragma unroll
                for (int j = 0; j < 4; j++)
                    acc[i][j] = __builtin_amdgcn_mfma_f32_16x16x32_f16(af[i], bf[j], acc[i][j], 0, 0, 0);
        }
    }

    float p[4][4];
#pragma unroll
    for (int i = 0; i < 4; i++)
#pragma unroll
        for (int r = 0; r < 4; r++) {
            int mloc = wm * 64 + i * 16 + quad * 4 + r;
            float s = 0.f;
#pragma unroll
            for (int j = 0; j < 4; j++) {
                int e = wn * 4 + j;
                s += sg[mloc][e] * (acc[i][j][r] + sbias[e][mi]);
            }
            p[i][r] = s;
        }

    __syncthreads();
    if (wn == 0) {
#pragma unroll
        for (int i = 0; i < 4; i++)
#pragma unroll
            for (int r = 0; r < 4; r++)
                sredf[(wm * 64 + i * 16 + quad * 4 + r) * 17 + mi] = p[i][r];
    }
    __syncthreads();
    if (wn == 1) {
#pragma unroll
        for (int i = 0; i < 4; i++)
#pragma unroll
            for (int r = 0; r < 4; r++) {
                int mrel = i * 16 + quad * 4 + r;
                float v = p[i][r] + sredf[(wm * 64 + mrel) * 17 + mi];
                if (ELU_ACT) v = elu_f(v);
                out[(size_t)(m0 + wm * 64 + mrel) * ldo + o0 + mi] = (OUT_T)v;
            }
    }
}

// ---------------------------------------------------------------------------
extern "C" void kernel_launch(void* const* d_in, const int* in_sizes, int n_in,
                              void* d_out, int out_size, void* d_ws, size_t ws_size,
                              hipStream_t stream)
{
    (void)in_sizes; (void)n_in; (void)out_size; (void)ws_size;
    const float* x   = (const float*)d_in[0];
    const float* z   = (const float*)d_in[1];
    const float* W0  = (const float*)d_in[2];
    const float* b0  = (const float*)d_in[3];
    const float* W1  = (const float*)d_in[4];
    const float* b1  = (const float*)d_in[5];
    const float* W2  = (const float*)d_in[6];
    const float* b2  = (const float*)d_in[7];
    const float* W3  = (const float*)d_in[8];
    const float* b3  = (const float*)d_in[9];
    const float* gW1 = (const float*)d_in[10];
    const float* gb1 = (const float*)d_in[11];
    const float* gW2 = (const float*)d_in[12];
    const float* gb2 = (const float*)d_in[13];
    const float* gW3 = (const float*)d_in[14];
    const float* gb3 = (const float*)d_in[15];

    char* p = (char*)d_ws;
    auto alloc = [&](size_t n) { char* r = p; p += (n + 255) & ~(size_t)255; return r; };
    _Float16* X0   = (_Float16*)alloc((size_t)4096 * 320 * 2);
    _Float16* h0   = (_Float16*)alloc((size_t)4096 * 576 * 2);
    _Float16* h1   = (_Float16*)alloc((size_t)4096 * 576 * 2);
    _Float16* h2   = (_Float16*)alloc((size_t)4096 * 576 * 2);
    _Float16* Wc0  = (_Float16*)alloc((size_t)8 * 512 * 320 * 2);
    _Float16* Wc1  = (_Float16*)alloc((size_t)8 * 512 * 576 * 2);
    _Float16* Wc2  = (_Float16*)alloc((size_t)8 * 512 * 576 * 2);
    _Float16* Wc3  = (_Float16*)alloc((size_t)8 * 96 * 512 * 2);
    float*    g    = (float*)alloc((size_t)4096 * 8 * 4);

    gating_conv<<<1024, 256, 0, stream>>>(x, z, gW1, gW2, gW3, gb1, gb2, gb3, g,
                                          W0, W1, W2, W3, X0, h0, h1, h2,
                                          Wc0, Wc1, Wc2, Wc3);

    blend64<true, _Float16><<<dim3(32, 32), 256, 0, stream>>>(X0, 320, Wc0, 320, 512, 320, g, b0, h0, 576);
    blend64<true, _Float16><<<dim3(32, 32), 256, 0, stream>>>(h0, 576, Wc1, 576, 512, 576, g, b1, h1, 576);
    blend64<true, _Float16><<<dim3(32, 32), 256, 0, stream>>>(h1, 576, Wc2, 576, 512, 576, g, b2, h2, 576);
    blend64<false, float><<<dim3(6, 32), 256, 0, stream>>>(h2, 576, Wc3, 512, 96, 512, g, b3, (float*)d_out, 96);
}

// Round 6
// 192.759 us; speedup vs baseline: 3.3120x; 1.1604x over previous
//
#include <hip/hip_runtime.h>
#include <hip/hip_fp16.h>

typedef _Float16 half8 __attribute__((ext_vector_type(8)));
typedef _Float16 half4 __attribute__((ext_vector_type(4)));
typedef float floatx4 __attribute__((ext_vector_type(4)));

__device__ __forceinline__ void async_ld16(const void* g, void* l) {
    __builtin_amdgcn_global_load_lds(
        (const __attribute__((address_space(1))) char*)g,
        (__attribute__((address_space(3))) char*)l, 16, 0, 0);
}

// fast ELU via HW v_exp_f32; |err| vs expm1f negligible against fp16 rounding.
__device__ __forceinline__ float elu_f(float v) {
    return v > 0.f ? v : (__expf(v) - 1.f);
}

__device__ __forceinline__ half4 cvt4(const float* src, int j4) {
    float4 f = ((const float4*)src)[j4];
    half4 h; h.x = (_Float16)f.x; h.y = (_Float16)f.y;
    h.z = (_Float16)f.z; h.w = (_Float16)f.w; return h;
}

// ---------------------------------------------------------------------------
// K1 convert_all: every fp32 input -> fp16 working buffer. No LDS, 1024 blocks.
//   X0 [4096][320] = [x|z]
//   h0/h1/h2 [4096][576]: cols 512..543 = z, 544..575 = 0 (K-pad)
//   Wc0 [8*512][320], Wc1/Wc2 [8*512][576] (pad cols 0), Wc3 [8*96][512]
//   gW1c [128][320], gW2c [128][128], gW3c [8][128]
// ---------------------------------------------------------------------------
__launch_bounds__(256)
__global__ void convert_all(const float* __restrict__ x, const float* __restrict__ z,
                            const float* __restrict__ W0, const float* __restrict__ W1,
                            const float* __restrict__ W2, const float* __restrict__ W3,
                            const float* __restrict__ gW1, const float* __restrict__ gW2,
                            const float* __restrict__ gW3,
                            _Float16* __restrict__ X0,
                            _Float16* __restrict__ h0, _Float16* __restrict__ h1,
                            _Float16* __restrict__ h2,
                            _Float16* __restrict__ Wc0, _Float16* __restrict__ Wc1,
                            _Float16* __restrict__ Wc2, _Float16* __restrict__ Wc3,
                            _Float16* __restrict__ gW1c, _Float16* __restrict__ gW2c,
                            _Float16* __restrict__ gW3c)
{
    const int S0 = 294912;                // X0 <- x   (row/72)
    const int S1 = 32768;                 // X0 <- z   (row/8)
    const int S2 = 327680;                // Wc0
    const int S3 = 589824;                // Wc1 <- W1 (row/144, pad)
    const int S4 = 589824;                // Wc2 <- W2
    const int S5 = 98304;                 // Wc3
    const int S6 = 196608;                // h z-cols + pad (3 x 4096 x 16)
    const int S7 = 10240;                 // gW1c
    const int S8 = 4096;                  // gW2c
    const int TOTAL = S0 + S1 + S2 + S3 + S4 + S5 + S6 + S7 + S8 + 256;
    const half4 hz = {};

    for (int i = blockIdx.x * blockDim.x + threadIdx.x; i < TOTAL;
         i += gridDim.x * blockDim.x) {
        int j = i;
        if (j < S0) {
            int r = j / 72, c = j - r * 72;
            *(half4*)(X0 + r * 320 + c * 4) = cvt4(x, j);
            continue;
        }
        j -= S0;
        if (j < S1) {
            int r = j / 8, c = j - r * 8;
            *(half4*)(X0 + r * 320 + 288 + c * 4) = cvt4(z, j);
            continue;
        }
        j -= S1;
        if (j < S2) { *(half4*)(Wc0 + j * 4) = cvt4(W0, j); continue; }
        j -= S2;
        if (j < S3) {
            int r = j / 144, c = j - r * 144;
            *(half4*)(Wc1 + r * 576 + c * 4) = (c < 136) ? cvt4(W1, r * 136 + c) : hz;
            continue;
        }
        j -= S3;
        if (j < S4) {
            int r = j / 144, c = j - r * 144;
            *(half4*)(Wc2 + r * 576 + c * 4) = (c < 136) ? cvt4(W2, r * 136 + c) : hz;
            continue;
        }
        j -= S4;
        if (j < S5) { *(half4*)(Wc3 + j * 4) = cvt4(W3, j); continue; }
        j -= S5;
        if (j < S6) {
            int buf = j >> 16;
            int r2 = j & 65535;
            int row = r2 >> 4, c = r2 & 15;
            _Float16* h = (buf == 0) ? h0 : ((buf == 1) ? h1 : h2);
            *(half4*)(h + row * 576 + 512 + c * 4) = (c < 8) ? cvt4(z, row * 8 + c) : hz;
            continue;
        }
        j -= S6;
        if (j < S7) { *(half4*)(gW1c + j * 4) = cvt4(gW1, j); continue; }
        j -= S7;
        if (j < S8) { *(half4*)(gW2c + j * 4) = cvt4(gW2, j); continue; }
        j -= S8;
        *(half4*)(gW3c + j * 4) = cvt4(gW3, j);
    }
}

// ---------------------------------------------------------------------------
// K2 gating_fast: 64 blocks x 4 waves; each wave owns 16 rows and runs the
// full 3-layer gating chain + softmax with NO __syncthreads. All operands
// fp16: a-frags from X0 (prefetched one kc ahead), b-frags direct half8
// loads from the small L2-hot fp16 gating weights (8 independent loads in
// flight per kc — no cvt dependency). One per-wave LDS tile (16x136) is
// reused for the L1->L2 and L2->L3 C-layout -> A-layout transposes.
// ---------------------------------------------------------------------------
__launch_bounds__(256)
__global__ void gating_fast(const _Float16* __restrict__ X0,
                            const _Float16* __restrict__ gW1c,
                            const _Float16* __restrict__ gW2c,
                            const _Float16* __restrict__ gW3c,
                            const float* __restrict__ gb1,
                            const float* __restrict__ gb2,
                            const float* __restrict__ gb3,
                            float* __restrict__ g)
{
    __shared__ _Float16 Tbuf[4 * 16 * 136];   // per-wave [16][136]

    const int tid = threadIdx.x;
    const int l = tid & 63;
    const int w = tid >> 6;
    const int quad = l >> 4;          // 0..3
    const int mi = l & 15;
    const int kq = quad * 8;
    const int mrow = (blockIdx.x * 4 + w) * 16;

    _Float16* T = Tbuf + w * (16 * 136);
    const _Float16* arow = X0 + (size_t)(mrow + mi) * 320;

    // ---- layer 1: X0 (K=320) @ gW1c^T -> 128, elu ----
    floatx4 acc1[8] = {};
    half8 a_nxt = *(const half8*)(arow + kq);
#pragma unroll
    for (int kc = 0; kc < 10; kc++) {
        const int k0 = kc * 32;
        half8 a = a_nxt;
        if (kc < 9) a_nxt = *(const half8*)(arow + k0 + 32 + kq);
#pragma unroll
        for (int t = 0; t < 8; t++) {
            half8 b = *(const half8*)(gW1c + (size_t)(t * 16 + mi) * 320 + k0 + kq);
            acc1[t] = __builtin_amdgcn_mfma_f32_16x16x32_f16(a, b, acc1[t], 0, 0, 0);
        }
    }
#pragma unroll
    for (int t = 0; t < 8; t++) {
        const int n = t * 16 + mi;
        const float bn = gb1[n];
#pragma unroll
        for (int r = 0; r < 4; r++)
            T[(quad * 4 + r) * 136 + n] = (_Float16)elu_f(acc1[t][r] + bn);
    }

    // ---- layer 2: T (K=128) @ gW2c^T -> 128, elu ----
    floatx4 acc2[8] = {};
#pragma unroll
    for (int kc = 0; kc < 4; kc++) {
        const int k0 = kc * 32;
        half8 a = *(const half8*)(T + mi * 136 + k0 + kq);
#pragma unroll
        for (int t = 0; t < 8; t++) {
            half8 b = *(const half8*)(gW2c + (size_t)(t * 16 + mi) * 128 + k0 + kq);
            acc2[t] = __builtin_amdgcn_mfma_f32_16x16x32_f16(a, b, acc2[t], 0, 0, 0);
        }
    }
    // reuse T (all T reads for L2 complete before these writes; same wave,
    // compiler-ordered via lgkmcnt)
#pragma unroll
    for (int t = 0; t < 8; t++) {
        const int n = t * 16 + mi;
        const float bn = gb2[n];
#pragma unroll
        for (int r = 0; r < 4; r++)
            T[(quad * 4 + r) * 136 + n] = (_Float16)elu_f(acc2[t][r] + bn);
    }

    // ---- layer 3: T (K=128) @ gW3c^T -> 8 logits, softmax ----
    floatx4 acc3 = {};
#pragma unroll
    for (int kc = 0; kc < 4; kc++) {
        const int k0 = kc * 32;
        half8 a = *(const half8*)(T + mi * 136 + k0 + kq);
        half8 b = (mi < 8) ? *(const half8*)(gW3c + (size_t)mi * 128 + k0 + kq) : half8{};
        acc3 = __builtin_amdgcn_mfma_f32_16x16x32_f16(a, b, acc3, 0, 0, 0);
    }
    const float gb = gb3[mi & 7];
#pragma unroll
    for (int r = 0; r < 4; r++) {
        float logit = acc3[r] + gb;            // lanes mi>=8: garbage, isolated
        float mx = logit;
        mx = fmaxf(mx, __shfl_xor(mx, 1));
        mx = fmaxf(mx, __shfl_xor(mx, 2));
        mx = fmaxf(mx, __shfl_xor(mx, 4));     // stays within the mi&8 half
        float e = __expf(logit - mx);
        float s = e;
        s += __shfl_xor(s, 1);
        s += __shfl_xor(s, 2);
        s += __shfl_xor(s, 4);
        if (mi < 8)
            g[(size_t)(mrow + quad * 4 + r) * 8 + mi] = e / s;
    }
}

// ---------------------------------------------------------------------------
// blended expert GEMM, BK=64 (unchanged — known-good):
//   out[m][o] = act( sum_e g[m][e]*( sum_k A[m][k]*W[e*Hdim+o][k] + bias[e*Hdim+o] ) )
// ---------------------------------------------------------------------------
template <bool ELU_ACT, typename OUT_T>
__launch_bounds__(256, 4)
__global__ void blend64(const _Float16* __restrict__ A, int lda,
                        const _Float16* __restrict__ W, int ldw,
                        int Hdim, int K,
                        const float* __restrict__ g,
                        const float* __restrict__ bias,
                        OUT_T* __restrict__ out, int ldo)
{
    __shared__ __align__(16) char smem_raw[32768];
    _Float16* sA = (_Float16*)smem_raw;            // [128][64]
    _Float16* sB = (_Float16*)(smem_raw + 16384);  // [128][64]
    float* sredf = (float*)smem_raw;               // [2][64][17] overlay (epilogue)
    __shared__ float sg[128][9];
    __shared__ float sbias[8][16];

    const int tid = threadIdx.x;
    const int l = tid & 63;
    const int w = tid >> 6;
    const int wm = w >> 1, wn = w & 1;
    const int o0 = blockIdx.x * 16;
    const int m0 = blockIdx.y * 128;

    for (int t = tid; t < 128 * 8; t += 256)
        sg[t >> 3][t & 7] = g[(size_t)(m0 + (t >> 3)) * 8 + (t & 7)];
    for (int t = tid; t < 128; t += 256)
        sbias[t >> 4][t & 15] = bias[(t >> 4) * Hdim + o0 + (t & 15)];

    const int lr = l >> 3;
    const int lc = l & 7;
    const int swz = lc ^ lr;

    const _Float16* gAp = A + (size_t)(m0 + w * 64 + lr) * lda + swz * 8;
    _Float16* lAp = sA + w * 4096;
    const int wb = w - 2;
    const int eb = wb * 4;
    const _Float16* gBe = W + ((size_t)eb * Hdim + o0 + lr) * ldw + swz * 8;
    const _Float16* gBo = gBe + (size_t)8 * ldw;
    _Float16* lBp = sB + wb * 4096;

    const int mi = l & 15, quad = l >> 4;
    const int cswz = mi & 7;
    const int offh0 = ((quad ^ cswz) * 8);
    const int offh1 = (((quad + 4) ^ cswz) * 8);
    const _Float16* rAb = sA + (wm * 64 + mi) * 64;
    const _Float16* rBb = sB + (wn * 64 + mi) * 64;

    floatx4 acc[4][4] = {};

    for (int k0 = 0; k0 < K; k0 += 64) {
        __syncthreads();
        if (w < 2) {
            const _Float16* gp = gAp + k0;
            _Float16* lp = lAp;
#pragma unroll
            for (int c = 0; c < 8; c++) {
                async_ld16(gp, lp);
                gp += (size_t)8 * lda;
                lp += 512;
            }
        } else {
            const _Float16* ge = gBe + k0;
            const _Float16* go = gBo + k0;
            _Float16* lp = lBp;
#pragma unroll
            for (int c2 = 0; c2 < 4; c2++) {
                async_ld16(ge, lp); lp += 512;
                async_ld16(go, lp); lp += 512;
                ge += (size_t)Hdim * ldw;
                go += (size_t)Hdim * ldw;
            }
        }
        __syncthreads();
#pragma unroll
        for (int h = 0; h < 2; h++) {
            const int off = h ? offh1 : offh0;
            half8 af[4], bf[4];
#pragma unroll
            for (int i = 0; i < 4; i++) af[i] = *(const half8*)(rAb + i * 1024 + off);
#pragma unroll
            for (int j = 0; j < 4; j++) bf[j] = *(const half8*)(rBb + j * 1024 + off);
#pragma unroll
            for (int i = 0; i < 4; i++)
#pragma unroll
                for (int j = 0; j < 4; j++)
                    acc[i][j] = __builtin_amdgcn_mfma_f32_16x16x32_f16(af[i], bf[j], acc[i][j], 0, 0, 0);
        }
    }

    float p[4][4];
#pragma unroll
    for (int i = 0; i < 4; i++)
#pragma unroll
        for (int r = 0; r < 4; r++) {
            int mloc = wm * 64 + i * 16 + quad * 4 + r;
            float s = 0.f;
#pragma unroll
            for (int j = 0; j < 4; j++) {
                int e = wn * 4 + j;
                s += sg[mloc][e] * (acc[i][j][r] + sbias[e][mi]);
            }
            p[i][r] = s;
        }

    __syncthreads();
    if (wn == 0) {
#pragma unroll
        for (int i = 0; i < 4; i++)
#pragma unroll
            for (int r = 0; r < 4; r++)
                sredf[(wm * 64 + i * 16 + quad * 4 + r) * 17 + mi] = p[i][r];
    }
    __syncthreads();
    if (wn == 1) {
#pragma unroll
        for (int i = 0; i < 4; i++)
#pragma unroll
            for (int r = 0; r < 4; r++) {
                int mrel = i * 16 + quad * 4 + r;
                float v = p[i][r] + sredf[(wm * 64 + mrel) * 17 + mi];
                if (ELU_ACT) v = elu_f(v);
                out[(size_t)(m0 + wm * 64 + mrel) * ldo + o0 + mi] = (OUT_T)v;
            }
    }
}

// ---------------------------------------------------------------------------
extern "C" void kernel_launch(void* const* d_in, const int* in_sizes, int n_in,
                              void* d_out, int out_size, void* d_ws, size_t ws_size,
                              hipStream_t stream)
{
    (void)in_sizes; (void)n_in; (void)out_size; (void)ws_size;
    const float* x   = (const float*)d_in[0];
    const float* z   = (const float*)d_in[1];
    const float* W0  = (const float*)d_in[2];
    const float* b0  = (const float*)d_in[3];
    const float* W1  = (const float*)d_in[4];
    const float* b1  = (const float*)d_in[5];
    const float* W2  = (const float*)d_in[6];
    const float* b2  = (const float*)d_in[7];
    const float* W3  = (const float*)d_in[8];
    const float* b3  = (const float*)d_in[9];
    const float* gW1 = (const float*)d_in[10];
    const float* gb1 = (const float*)d_in[11];
    const float* gW2 = (const float*)d_in[12];
    const float* gb2 = (const float*)d_in[13];
    const float* gW3 = (const float*)d_in[14];
    const float* gb3 = (const float*)d_in[15];

    char* p = (char*)d_ws;
    auto alloc = [&](size_t n) { char* r = p; p += (n + 255) & ~(size_t)255; return r; };
    _Float16* X0   = (_Float16*)alloc((size_t)4096 * 320 * 2);
    _Float16* h0   = (_Float16*)alloc((size_t)4096 * 576 * 2);
    _Float16* h1   = (_Float16*)alloc((size_t)4096 * 576 * 2);
    _Float16* h2   = (_Float16*)alloc((size_t)4096 * 576 * 2);
    _Float16* Wc0  = (_Float16*)alloc((size_t)8 * 512 * 320 * 2);
    _Float16* Wc1  = (_Float16*)alloc((size_t)8 * 512 * 576 * 2);
    _Float16* Wc2  = (_Float16*)alloc((size_t)8 * 512 * 576 * 2);
    _Float16* Wc3  = (_Float16*)alloc((size_t)8 * 96 * 512 * 2);
    _Float16* gW1c = (_Float16*)alloc((size_t)128 * 320 * 2);
    _Float16* gW2c = (_Float16*)alloc((size_t)128 * 128 * 2);
    _Float16* gW3c = (_Float16*)alloc((size_t)8 * 128 * 2);
    float*    g    = (float*)alloc((size_t)4096 * 8 * 4);

    convert_all<<<1024, 256, 0, stream>>>(x, z, W0, W1, W2, W3, gW1, gW2, gW3,
                                          X0, h0, h1, h2, Wc0, Wc1, Wc2, Wc3,
                                          gW1c, gW2c, gW3c);

    gating_fast<<<64, 256, 0, stream>>>(X0, gW1c, gW2c, gW3c, gb1, gb2, gb3, g);

    blend64<true, _Float16><<<dim3(32, 32), 256, 0, stream>>>(X0, 320, Wc0, 320, 512, 320, g, b0, h0, 576);
    blend64<true, _Float16><<<dim3(32, 32), 256, 0, stream>>>(h0, 576, Wc1, 576, 512, 576, g, b1, h1, 576);
    blend64<true, _Float16><<<dim3(32, 32), 256, 0, stream>>>(h1, 576, Wc2, 576, 512, 576, g, b2, h2, 576);
    blend64<false, float><<<dim3(6, 32), 256, 0, stream>>>(h2, 576, Wc3, 512, 96, 512, g, b3, (float*)d_out, 96);
}

// Round 7
// 191.941 us; speedup vs baseline: 3.3261x; 1.0043x over previous
//
#include <hip/hip_runtime.h>
#include <hip/hip_fp16.h>

typedef _Float16 half8 __attribute__((ext_vector_type(8)));
typedef _Float16 half4 __attribute__((ext_vector_type(4)));
typedef float floatx4 __attribute__((ext_vector_type(4)));

__device__ __forceinline__ void async_ld16(const void* g, void* l) {
    __builtin_amdgcn_global_load_lds(
        (const __attribute__((address_space(1))) char*)g,
        (__attribute__((address_space(3))) char*)l, 16, 0, 0);
}

// fast ELU via HW v_exp_f32; |err| vs expm1f negligible against fp16 rounding.
__device__ __forceinline__ float elu_f(float v) {
    return v > 0.f ? v : (__expf(v) - 1.f);
}

__device__ __forceinline__ half4 cvt4(const float* src, int j4) {
    float4 f = ((const float4*)src)[j4];
    half4 h; h.x = (_Float16)f.x; h.y = (_Float16)f.y;
    h.z = (_Float16)f.z; h.w = (_Float16)f.w; return h;
}

// ---------------------------------------------------------------------------
// K1 convert_all: every fp32 input -> fp16 working buffer. No LDS, 1024 blocks.
// ---------------------------------------------------------------------------
__launch_bounds__(256)
__global__ void convert_all(const float* __restrict__ x, const float* __restrict__ z,
                            const float* __restrict__ W0, const float* __restrict__ W1,
                            const float* __restrict__ W2, const float* __restrict__ W3,
                            const float* __restrict__ gW1, const float* __restrict__ gW2,
                            const float* __restrict__ gW3,
                            _Float16* __restrict__ X0,
                            _Float16* __restrict__ h0, _Float16* __restrict__ h1,
                            _Float16* __restrict__ h2,
                            _Float16* __restrict__ Wc0, _Float16* __restrict__ Wc1,
                            _Float16* __restrict__ Wc2, _Float16* __restrict__ Wc3,
                            _Float16* __restrict__ gW1c, _Float16* __restrict__ gW2c,
                            _Float16* __restrict__ gW3c)
{
    const int S0 = 294912;                // X0 <- x   (row/72)
    const int S1 = 32768;                 // X0 <- z   (row/8)
    const int S2 = 327680;                // Wc0
    const int S3 = 589824;                // Wc1 <- W1 (row/144, pad)
    const int S4 = 589824;                // Wc2 <- W2
    const int S5 = 98304;                 // Wc3
    const int S6 = 196608;                // h z-cols + pad (3 x 4096 x 16)
    const int S7 = 10240;                 // gW1c
    const int S8 = 4096;                  // gW2c
    const int TOTAL = S0 + S1 + S2 + S3 + S4 + S5 + S6 + S7 + S8 + 256;
    const half4 hz = {};

    for (int i = blockIdx.x * blockDim.x + threadIdx.x; i < TOTAL;
         i += gridDim.x * blockDim.x) {
        int j = i;
        if (j < S0) {
            int r = j / 72, c = j - r * 72;
            *(half4*)(X0 + r * 320 + c * 4) = cvt4(x, j);
            continue;
        }
        j -= S0;
        if (j < S1) {
            int r = j / 8, c = j - r * 8;
            *(half4*)(X0 + r * 320 + 288 + c * 4) = cvt4(z, j);
            continue;
        }
        j -= S1;
        if (j < S2) { *(half4*)(Wc0 + j * 4) = cvt4(W0, j); continue; }
        j -= S2;
        if (j < S3) {
            int r = j / 144, c = j - r * 144;
            *(half4*)(Wc1 + r * 576 + c * 4) = (c < 136) ? cvt4(W1, r * 136 + c) : hz;
            continue;
        }
        j -= S3;
        if (j < S4) {
            int r = j / 144, c = j - r * 144;
            *(half4*)(Wc2 + r * 576 + c * 4) = (c < 136) ? cvt4(W2, r * 136 + c) : hz;
            continue;
        }
        j -= S4;
        if (j < S5) { *(half4*)(Wc3 + j * 4) = cvt4(W3, j); continue; }
        j -= S5;
        if (j < S6) {
            int buf = j >> 16;
            int r2 = j & 65535;
            int row = r2 >> 4, c = r2 & 15;
            _Float16* h = (buf == 0) ? h0 : ((buf == 1) ? h1 : h2);
            *(half4*)(h + row * 576 + 512 + c * 4) = (c < 8) ? cvt4(z, row * 8 + c) : hz;
            continue;
        }
        j -= S6;
        if (j < S7) { *(half4*)(gW1c + j * 4) = cvt4(gW1, j); continue; }
        j -= S7;
        if (j < S8) { *(half4*)(gW2c + j * 4) = cvt4(gW2, j); continue; }
        j -= S8;
        *(half4*)(gW3c + j * 4) = cvt4(gW3, j);
    }
}

// ---------------------------------------------------------------------------
// K2 gating_fast (unchanged — known-good, ~4 µs): 64 blocks x 4 waves, each
// wave owns 16 rows, full 3-layer chain + softmax, no __syncthreads.
// ---------------------------------------------------------------------------
__launch_bounds__(256)
__global__ void gating_fast(const _Float16* __restrict__ X0,
                            const _Float16* __restrict__ gW1c,
                            const _Float16* __restrict__ gW2c,
                            const _Float16* __restrict__ gW3c,
                            const float* __restrict__ gb1,
                            const float* __restrict__ gb2,
                            const float* __restrict__ gb3,
                            float* __restrict__ g)
{
    __shared__ _Float16 Tbuf[4 * 16 * 136];   // per-wave [16][136]

    const int tid = threadIdx.x;
    const int l = tid & 63;
    const int w = tid >> 6;
    const int quad = l >> 4;
    const int mi = l & 15;
    const int kq = quad * 8;
    const int mrow = (blockIdx.x * 4 + w) * 16;

    _Float16* T = Tbuf + w * (16 * 136);
    const _Float16* arow = X0 + (size_t)(mrow + mi) * 320;

    floatx4 acc1[8] = {};
    half8 a_nxt = *(const half8*)(arow + kq);
#pragma unroll
    for (int kc = 0; kc < 10; kc++) {
        const int k0 = kc * 32;
        half8 a = a_nxt;
        if (kc < 9) a_nxt = *(const half8*)(arow + k0 + 32 + kq);
#pragma unroll
        for (int t = 0; t < 8; t++) {
            half8 b = *(const half8*)(gW1c + (size_t)(t * 16 + mi) * 320 + k0 + kq);
            acc1[t] = __builtin_amdgcn_mfma_f32_16x16x32_f16(a, b, acc1[t], 0, 0, 0);
        }
    }
#pragma unroll
    for (int t = 0; t < 8; t++) {
        const int n = t * 16 + mi;
        const float bn = gb1[n];
#pragma unroll
        for (int r = 0; r < 4; r++)
            T[(quad * 4 + r) * 136 + n] = (_Float16)elu_f(acc1[t][r] + bn);
    }

    floatx4 acc2[8] = {};
#pragma unroll
    for (int kc = 0; kc < 4; kc++) {
        const int k0 = kc * 32;
        half8 a = *(const half8*)(T + mi * 136 + k0 + kq);
#pragma unroll
        for (int t = 0; t < 8; t++) {
            half8 b = *(const half8*)(gW2c + (size_t)(t * 16 + mi) * 128 + k0 + kq);
            acc2[t] = __builtin_amdgcn_mfma_f32_16x16x32_f16(a, b, acc2[t], 0, 0, 0);
        }
    }
#pragma unroll
    for (int t = 0; t < 8; t++) {
        const int n = t * 16 + mi;
        const float bn = gb2[n];
#pragma unroll
        for (int r = 0; r < 4; r++)
            T[(quad * 4 + r) * 136 + n] = (_Float16)elu_f(acc2[t][r] + bn);
    }

    floatx4 acc3 = {};
#pragma unroll
    for (int kc = 0; kc < 4; kc++) {
        const int k0 = kc * 32;
        half8 a = *(const half8*)(T + mi * 136 + k0 + kq);
        half8 b = (mi < 8) ? *(const half8*)(gW3c + (size_t)mi * 128 + k0 + kq) : half8{};
        acc3 = __builtin_amdgcn_mfma_f32_16x16x32_f16(a, b, acc3, 0, 0, 0);
    }
    const float gb = gb3[mi & 7];
#pragma unroll
    for (int r = 0; r < 4; r++) {
        float logit = acc3[r] + gb;
        float mx = logit;
        mx = fmaxf(mx, __shfl_xor(mx, 1));
        mx = fmaxf(mx, __shfl_xor(mx, 2));
        mx = fmaxf(mx, __shfl_xor(mx, 4));
        float e = __expf(logit - mx);
        float s = e;
        s += __shfl_xor(s, 1);
        s += __shfl_xor(s, 2);
        s += __shfl_xor(s, 4);
        if (mi < 8)
            g[(size_t)(mrow + quad * 4 + r) * 8 + mi] = e / s;
    }
}

// ---------------------------------------------------------------------------
// blended expert GEMM, BK=64, 1-D grid with XCD-aware swizzle (SWZ=true):
// xcd = id&7 owns an 8(by) x 16(bx) region of the 32x32 tile grid ->
// per-XCD L2 working set 8 A-tiles + 16 B-tiles = 3.5 MB < 4 MB, so the
// per-iteration staging loads hit XCD-local L2 (~200cyc) instead of
// thrashing to L3/HBM (~500-900cyc). Mapping is speed-only (G16-safe).
// ---------------------------------------------------------------------------
template <bool ELU_ACT, bool SWZ, typename OUT_T>
__launch_bounds__(256, 4)
__global__ void blend64(const _Float16* __restrict__ A, int lda,
                        const _Float16* __restrict__ W, int ldw,
                        int Hdim, int K,
                        const float* __restrict__ g,
                        const float* __restrict__ bias,
                        OUT_T* __restrict__ out, int ldo)
{
    __shared__ __align__(16) char smem_raw[32768];
    _Float16* sA = (_Float16*)smem_raw;            // [128][64]
    _Float16* sB = (_Float16*)(smem_raw + 16384);  // [128][64]
    float* sredf = (float*)smem_raw;               // [2][64][17] overlay (epilogue)
    __shared__ float sg[128][9];
    __shared__ float sbias[8][16];

    const int tid = threadIdx.x;
    const int l = tid & 63;
    const int w = tid >> 6;
    const int wm = w >> 1, wn = w & 1;

    int by, bx;
    if (SWZ) {
        const int id = blockIdx.x;
        const int r = id & 7, q = id >> 3;       // r = XCD (round-robin dispatch)
        by = (r >> 1) * 8 + (q & 7);             // 8 by-tiles per XCD region
        bx = (r & 1) * 16 + (q >> 3);            // 16 bx-tiles per XCD region
    } else {
        const int id = blockIdx.x;
        by = id / 6;
        bx = id - by * 6;
    }
    const int o0 = bx * 16;
    const int m0 = by * 128;

    for (int t = tid; t < 128 * 8; t += 256)
        sg[t >> 3][t & 7] = g[(size_t)(m0 + (t >> 3)) * 8 + (t & 7)];
    for (int t = tid; t < 128; t += 256)
        sbias[t >> 4][t & 15] = bias[(t >> 4) * Hdim + o0 + (t & 15)];

    const int lr = l >> 3;
    const int lc = l & 7;
    const int swz = lc ^ lr;

    const _Float16* gAp = A + (size_t)(m0 + w * 64 + lr) * lda + swz * 8;
    _Float16* lAp = sA + w * 4096;
    const int wb = w - 2;
    const int eb = wb * 4;
    const _Float16* gBe = W + ((size_t)eb * Hdim + o0 + lr) * ldw + swz * 8;
    const _Float16* gBo = gBe + (size_t)8 * ldw;
    _Float16* lBp = sB + wb * 4096;

    const int mi = l & 15, quad = l >> 4;
    const int cswz = mi & 7;
    const int offh0 = ((quad ^ cswz) * 8);
    const int offh1 = (((quad + 4) ^ cswz) * 8);
    const _Float16* rAb = sA + (wm * 64 + mi) * 64;
    const _Float16* rBb = sB + (wn * 64 + mi) * 64;

    floatx4 acc[4][4] = {};

    for (int k0 = 0; k0 < K; k0 += 64) {
        __syncthreads();
        if (w < 2) {
            const _Float16* gp = gAp + k0;
            _Float16* lp = lAp;
#pragma unroll
            for (int c = 0; c < 8; c++) {
                async_ld16(gp, lp);
                gp += (size_t)8 * lda;
                lp += 512;
            }
        } else {
            const _Float16* ge = gBe + k0;
            const _Float16* go = gBo + k0;
            _Float16* lp = lBp;
#pragma unroll
            for (int c2 = 0; c2 < 4; c2++) {
                async_ld16(ge, lp); lp += 512;
                async_ld16(go, lp); lp += 512;
                ge += (size_t)Hdim * ldw;
                go += (size_t)Hdim * ldw;
            }
        }
        __syncthreads();
#pragma unroll
        for (int h = 0; h < 2; h++) {
            const int off = h ? offh1 : offh0;
            half8 af[4], bf[4];
#pragma unroll
            for (int i = 0; i < 4; i++) af[i] = *(const half8*)(rAb + i * 1024 + off);
#pragma unroll
            for (int j = 0; j < 4; j++) bf[j] = *(const half8*)(rBb + j * 1024 + off);
#pragma unroll
            for (int i = 0; i < 4; i++)
#pragma unroll
                for (int j = 0; j < 4; j++)
                    acc[i][j] = __builtin_amdgcn_mfma_f32_16x16x32_f16(af[i], bf[j], acc[i][j], 0, 0, 0);
        }
    }

    float p[4][4];
#pragma unroll
    for (int i = 0; i < 4; i++)
#pragma unroll
        for (int r = 0; r < 4; r++) {
            int mloc = wm * 64 + i * 16 + quad * 4 + r;
            float s = 0.f;
#pragma unroll
            for (int j = 0; j < 4; j++) {
                int e = wn * 4 + j;
                s += sg[mloc][e] * (acc[i][j][r] + sbias[e][mi]);
            }
            p[i][r] = s;
        }

    __syncthreads();
    if (wn == 0) {
#pragma unroll
        for (int i = 0; i < 4; i++)
#pragma unroll
            for (int r = 0; r < 4; r++)
                sredf[(wm * 64 + i * 16 + quad * 4 + r) * 17 + mi] = p[i][r];
    }
    __syncthreads();
    if (wn == 1) {
#pragma unroll
        for (int i = 0; i < 4; i++)
#pragma unroll
            for (int r = 0; r < 4; r++) {
                int mrel = i * 16 + quad * 4 + r;
                float v = p[i][r] + sredf[(wm * 64 + mrel) * 17 + mi];
                if (ELU_ACT) v = elu_f(v);
                out[(size_t)(m0 + wm * 64 + mrel) * ldo + o0 + mi] = (OUT_T)v;
            }
    }
}

// ---------------------------------------------------------------------------
extern "C" void kernel_launch(void* const* d_in, const int* in_sizes, int n_in,
                              void* d_out, int out_size, void* d_ws, size_t ws_size,
                              hipStream_t stream)
{
    (void)in_sizes; (void)n_in; (void)out_size; (void)ws_size;
    const float* x   = (const float*)d_in[0];
    const float* z   = (const float*)d_in[1];
    const float* W0  = (const float*)d_in[2];
    const float* b0  = (const float*)d_in[3];
    const float* W1  = (const float*)d_in[4];
    const float* b1  = (const float*)d_in[5];
    const float* W2  = (const float*)d_in[6];
    const float* b2  = (const float*)d_in[7];
    const float* W3  = (const float*)d_in[8];
    const float* b3  = (const float*)d_in[9];
    const float* gW1 = (const float*)d_in[10];
    const float* gb1 = (const float*)d_in[11];
    const float* gW2 = (const float*)d_in[12];
    const float* gb2 = (const float*)d_in[13];
    const float* gW3 = (const float*)d_in[14];
    const float* gb3 = (const float*)d_in[15];

    char* p = (char*)d_ws;
    auto alloc = [&](size_t n) { char* r = p; p += (n + 255) & ~(size_t)255; return r; };
    _Float16* X0   = (_Float16*)alloc((size_t)4096 * 320 * 2);
    _Float16* h0   = (_Float16*)alloc((size_t)4096 * 576 * 2);
    _Float16* h1   = (_Float16*)alloc((size_t)4096 * 576 * 2);
    _Float16* h2   = (_Float16*)alloc((size_t)4096 * 576 * 2);
    _Float16* Wc0  = (_Float16*)alloc((size_t)8 * 512 * 320 * 2);
    _Float16* Wc1  = (_Float16*)alloc((size_t)8 * 512 * 576 * 2);
    _Float16* Wc2  = (_Float16*)alloc((size_t)8 * 512 * 576 * 2);
    _Float16* Wc3  = (_Float16*)alloc((size_t)8 * 96 * 512 * 2);
    _Float16* gW1c = (_Float16*)alloc((size_t)128 * 320 * 2);
    _Float16* gW2c = (_Float16*)alloc((size_t)128 * 128 * 2);
    _Float16* gW3c = (_Float16*)alloc((size_t)8 * 128 * 2);
    float*    g    = (float*)alloc((size_t)4096 * 8 * 4);

    convert_all<<<1024, 256, 0, stream>>>(x, z, W0, W1, W2, W3, gW1, gW2, gW3,
                                          X0, h0, h1, h2, Wc0, Wc1, Wc2, Wc3,
                                          gW1c, gW2c, gW3c);

    gating_fast<<<64, 256, 0, stream>>>(X0, gW1c, gW2c, gW3c, gb1, gb2, gb3, g);

    blend64<true, true, _Float16><<<1024, 256, 0, stream>>>(X0, 320, Wc0, 320, 512, 320, g, b0, h0, 576);
    blend64<true, true, _Float16><<<1024, 256, 0, stream>>>(h0, 576, Wc1, 576, 512, 576, g, b1, h1, 576);
    blend64<true, true, _Float16><<<1024, 256, 0, stream>>>(h1, 576, Wc2, 576, 512, 576, g, b2, h2, 576);
    blend64<false, false, float><<<192, 256, 0, stream>>>(h2, 576, Wc3, 512, 96, 512, g, b3, (float*)d_out, 96);
}